// Round 1
// baseline (1121.154 us; speedup 1.0000x reference)
//
#include <hip/hip_runtime.h>

#define CLS 10000
#define BATCH 8192

// Combine two online-softmax partial states (m = running max, s = sum of exp(v - m)).
__device__ __forceinline__ void combine_ms(float& m, float& s, float om, float os) {
  float nm = fmaxf(m, om);
  s = s * __expf(m - nm) + os * __expf(om - nm);
  m = nm;
}

// One block per batch row. Single pass over x[b,:] and matrix[target[b],:]:
// online softmax (max+sumexp), argmax, and dot(softlabel, x).
// loss_b = logZ_b - dot_b   (softlabel rows sum to 1)
__global__ __launch_bounds__(256) void rowstats_kernel(
    const float* __restrict__ x, const int* __restrict__ target,
    const float* __restrict__ matrix, float* __restrict__ loss_out,
    float* __restrict__ row_logZ, int* __restrict__ row_correct)
{
  int b = blockIdx.x;
  int t = target[b];
  const float4* xr = (const float4*)(x + (size_t)b * CLS);
  const float4* mr = (const float4*)(matrix + (size_t)t * CLS);

  float m = -3.4e38f, s = 0.f, dot = 0.f;
  float bestv = -3.4e38f;
  int besti = 0x7fffffff;

  for (int i = threadIdx.x; i < CLS / 4; i += 256) {
    float4 xv = xr[i];
    float4 mv = mr[i];
    dot += xv.x * mv.x;
    dot += xv.y * mv.y;
    dot += xv.z * mv.z;
    dot += xv.w * mv.w;
    float vals[4] = {xv.x, xv.y, xv.z, xv.w};
#pragma unroll
    for (int j = 0; j < 4; ++j) {
      float v = vals[j];
      int idx = 4 * i + j;
      // first-occurrence argmax semantics: strict >, ties -> lower index
      if (v > bestv || (v == bestv && idx < besti)) { bestv = v; besti = idx; }
      float nm = fmaxf(m, v);
      s = s * __expf(m - nm) + __expf(v - nm);
      m = nm;
    }
  }

  // wave (64-lane) reduction
#pragma unroll
  for (int off = 32; off > 0; off >>= 1) {
    float om = __shfl_down(m, off);
    float os = __shfl_down(s, off);
    float od = __shfl_down(dot, off);
    float ov = __shfl_down(bestv, off);
    int   oi = __shfl_down(besti, off);
    combine_ms(m, s, om, os);
    dot += od;
    if (ov > bestv || (ov == bestv && oi < besti)) { bestv = ov; besti = oi; }
  }

  // cross-wave (4 waves) reduction via LDS
  __shared__ float sm[4], ss[4], sd[4], sv[4];
  __shared__ int si[4];
  int wave = threadIdx.x >> 6;
  if ((threadIdx.x & 63) == 0) {
    sm[wave] = m; ss[wave] = s; sd[wave] = dot; sv[wave] = bestv; si[wave] = besti;
  }
  __syncthreads();
  if (threadIdx.x == 0) {
    for (int w = 1; w < 4; ++w) {
      combine_ms(m, s, sm[w], ss[w]);
      dot += sd[w];
      if (sv[w] > bestv || (sv[w] == bestv && si[w] < besti)) { bestv = sv[w]; besti = si[w]; }
    }
    float logZ = m + __logf(s);
    row_logZ[b] = logZ;
    row_correct[b] = (besti == t) ? 1 : 0;
    atomicAdd(loss_out, (logZ - dot) * (1.0f / BATCH));
  }
}

// Plain coalesced dword grid-stride copy (dst is +1 float off 16B alignment,
// so float4 stores are not legal; dword stores still coalesce to full lines).
__global__ void copy_kernel(const float* __restrict__ src, float* __restrict__ dst,
                            long long n)
{
  long long stride = (long long)gridDim.x * blockDim.x;
  for (long long i = (long long)blockIdx.x * blockDim.x + threadIdx.x; i < n; i += stride)
    dst[i] = src[i];
}

// For rows where pred == target: out_grad[t, :] += softmax(x[b, :]); out_count[t] += 1.
// Expected ~1 active block out of 8192 (P(correct) ~ 1/C for random logits).
__global__ __launch_bounds__(256) void scatter_kernel(
    const float* __restrict__ x, const int* __restrict__ target,
    const float* __restrict__ row_logZ, const int* __restrict__ row_correct,
    float* __restrict__ out_grad, float* __restrict__ out_count)
{
  int b = blockIdx.x;
  if (!row_correct[b]) return;
  int t = target[b];
  float lz = row_logZ[b];
  const float* xr = x + (size_t)b * CLS;
  float* gr = out_grad + (size_t)t * CLS;
  for (int c = threadIdx.x; c < CLS; c += 256)
    atomicAdd(&gr[c], __expf(xr[c] - lz));
  if (threadIdx.x == 0) atomicAdd(&out_count[t], 1.0f);
}

extern "C" void kernel_launch(void* const* d_in, const int* in_sizes, int n_in,
                              void* d_out, int out_size, void* d_ws, size_t ws_size,
                              hipStream_t stream)
{
  const float* x          = (const float*)d_in[0];
  const int*   target     = (const int*)d_in[1];
  const float* matrix     = (const float*)d_in[2];
  const float* grad_state = (const float*)d_in[3];
  const float* count      = (const float*)d_in[4];

  float* out       = (float*)d_out;
  float* out_loss  = out;                       // [1]
  float* out_grad  = out + 1;                   // [C*C]
  float* out_count = out + 1 + (long long)CLS * CLS;  // [C]

  float* row_logZ    = (float*)d_ws;
  int*   row_correct = (int*)((char*)d_ws + BATCH * sizeof(float));

  hipMemsetAsync(out_loss, 0, sizeof(float), stream);

  rowstats_kernel<<<BATCH, 256, 0, stream>>>(x, target, matrix, out_loss,
                                             row_logZ, row_correct);
  copy_kernel<<<16384, 256, 0, stream>>>(grad_state, out_grad, (long long)CLS * CLS);
  copy_kernel<<<64, 256, 0, stream>>>(count, out_count, (long long)CLS);
  scatter_kernel<<<BATCH, 256, 0, stream>>>(x, target, row_logZ, row_correct,
                                            out_grad, out_count);
}

// Round 2
// 1065.178 us; speedup vs baseline: 1.0526x; 1.0526x over previous
//
#include <hip/hip_runtime.h>

#define CLS 10000
#define BATCH 8192
#define NGRAD 100000000LL  // CLS*CLS

// Combine two online-softmax partial states (m = running max, s = sum of exp(v - m)).
__device__ __forceinline__ void combine_ms(float& m, float& s, float om, float os) {
  float nm = fmaxf(m, om);
  s = s * __expf(m - nm) + os * __expf(om - nm);
  m = nm;
}

// One block per batch row. Single pass over x[b,:] and matrix[target[b],:]:
// online softmax (max+sumexp), argmax, and dot(softlabel, x).
// loss_b = logZ_b - dot_b   (softlabel rows sum to 1).
// Per-row results go to workspace -> no same-address atomic storm.
__global__ __launch_bounds__(256) void rowstats_kernel(
    const float* __restrict__ x, const int* __restrict__ target,
    const float* __restrict__ matrix, float* __restrict__ row_loss,
    float* __restrict__ row_logZ, int* __restrict__ row_correct)
{
  int b = blockIdx.x;
  int t = target[b];
  const float4* xr = (const float4*)(x + (size_t)b * CLS);
  const float4* mr = (const float4*)(matrix + (size_t)t * CLS);

  float m = -3.4e38f, s = 0.f, dot = 0.f;
  float bestv = -3.4e38f;
  int besti = 0x7fffffff;

  for (int i = threadIdx.x; i < CLS / 4; i += 256) {
    float4 xv = xr[i];
    float4 mv = mr[i];
    dot += xv.x * mv.x;
    dot += xv.y * mv.y;
    dot += xv.z * mv.z;
    dot += xv.w * mv.w;
    float vals[4] = {xv.x, xv.y, xv.z, xv.w};
#pragma unroll
    for (int j = 0; j < 4; ++j) {
      float v = vals[j];
      int idx = 4 * i + j;
      // first-occurrence argmax semantics: strict >, ties -> lower index
      if (v > bestv || (v == bestv && idx < besti)) { bestv = v; besti = idx; }
      float nm = fmaxf(m, v);
      s = s * __expf(m - nm) + __expf(v - nm);
      m = nm;
    }
  }

  // wave (64-lane) reduction
#pragma unroll
  for (int off = 32; off > 0; off >>= 1) {
    float om = __shfl_down(m, off);
    float os = __shfl_down(s, off);
    float od = __shfl_down(dot, off);
    float ov = __shfl_down(bestv, off);
    int   oi = __shfl_down(besti, off);
    combine_ms(m, s, om, os);
    dot += od;
    if (ov > bestv || (ov == bestv && oi < besti)) { bestv = ov; besti = oi; }
  }

  // cross-wave (4 waves) reduction via LDS
  __shared__ float sm[4], ss[4], sd[4], sv[4];
  __shared__ int si[4];
  int wave = threadIdx.x >> 6;
  if ((threadIdx.x & 63) == 0) {
    sm[wave] = m; ss[wave] = s; sd[wave] = dot; sv[wave] = bestv; si[wave] = besti;
  }
  __syncthreads();
  if (threadIdx.x == 0) {
    for (int w = 1; w < 4; ++w) {
      combine_ms(m, s, sm[w], ss[w]);
      dot += sd[w];
      if (sv[w] > bestv || (sv[w] == bestv && si[w] < besti)) { bestv = sv[w]; besti = si[w]; }
    }
    float logZ = m + __logf(s);
    row_logZ[b] = logZ;
    row_correct[b] = (besti == t) ? 1 : 0;
    row_loss[b] = logZ - dot;
  }
}

// Copy grad_state -> out+1 with float4-ALIGNED STORES.
// out+4 is 16B aligned; prologue covers out[1..3], tail covers out[NGRAD].
// Main body: ((float4*)(out+4))[k] = {src[3+4k..6+4k]}, k in [0, 24999999).
__global__ __launch_bounds__(256) void copy_grad_kernel(
    const float* __restrict__ src, float* __restrict__ out)
{
  const long long N4 = (NGRAD - 4) / 4;  // 24999999 aligned float4 stores
  long long k = (long long)blockIdx.x * blockDim.x + threadIdx.x;
  if (k == 0) {
    out[1] = src[0]; out[2] = src[1]; out[3] = src[2];
    out[NGRAD] = src[NGRAD - 1];
  }
  if (k < N4) {
    const float* s = src + 3 + 4 * k;
    float4 v;
    v.x = s[0]; v.y = s[1]; v.z = s[2]; v.w = s[3];
    ((float4*)(out + 4))[k] = v;
  }
}

// Single block: reduce 8192 per-row losses -> out[0] (mean), and copy count.
__global__ __launch_bounds__(256) void finalize_kernel(
    const float* __restrict__ row_loss, const float* __restrict__ count,
    float* __restrict__ out_loss, float* __restrict__ out_count)
{
  float acc = 0.f;
  for (int i = threadIdx.x; i < BATCH; i += 256) acc += row_loss[i];
#pragma unroll
  for (int off = 32; off > 0; off >>= 1) acc += __shfl_down(acc, off);
  __shared__ float sw[4];
  if ((threadIdx.x & 63) == 0) sw[threadIdx.x >> 6] = acc;
  __syncthreads();
  if (threadIdx.x == 0)
    out_loss[0] = (sw[0] + sw[1] + sw[2] + sw[3]) * (1.0f / BATCH);
  for (int c = threadIdx.x; c < CLS; c += 256) out_count[c] = count[c];
}

// For rows where pred == target: out_grad[t, :] += softmax(x[b, :]); out_count[t] += 1.
// Expected ~1 active block out of 8192 (P(correct) ~ 1/C for random logits).
__global__ __launch_bounds__(256) void scatter_kernel(
    const float* __restrict__ x, const int* __restrict__ target,
    const float* __restrict__ row_logZ, const int* __restrict__ row_correct,
    float* __restrict__ out_grad, float* __restrict__ out_count)
{
  int b = blockIdx.x;
  if (!row_correct[b]) return;
  int t = target[b];
  float lz = row_logZ[b];
  const float* xr = x + (size_t)b * CLS;
  float* gr = out_grad + (size_t)t * CLS;
  for (int c = threadIdx.x; c < CLS; c += 256)
    atomicAdd(&gr[c], __expf(xr[c] - lz));
  if (threadIdx.x == 0) atomicAdd(&out_count[t], 1.0f);
}

extern "C" void kernel_launch(void* const* d_in, const int* in_sizes, int n_in,
                              void* d_out, int out_size, void* d_ws, size_t ws_size,
                              hipStream_t stream)
{
  const float* x          = (const float*)d_in[0];
  const int*   target     = (const int*)d_in[1];
  const float* matrix     = (const float*)d_in[2];
  const float* grad_state = (const float*)d_in[3];
  const float* count      = (const float*)d_in[4];

  float* out       = (float*)d_out;
  float* out_loss  = out;                 // [1]
  float* out_grad  = out + 1;             // [C*C]
  float* out_count = out + 1 + NGRAD;     // [C]

  float* row_loss    = (float*)d_ws;                          // [BATCH]
  float* row_logZ    = row_loss + BATCH;                      // [BATCH]
  int*   row_correct = (int*)(row_logZ + BATCH);              // [BATCH]

  rowstats_kernel<<<BATCH, 256, 0, stream>>>(x, target, matrix, row_loss,
                                             row_logZ, row_correct);
  const long long N4 = (NGRAD - 4) / 4;
  int copy_blocks = (int)((N4 + 255) / 256);
  copy_grad_kernel<<<copy_blocks, 256, 0, stream>>>(grad_state, out);
  finalize_kernel<<<1, 256, 0, stream>>>(row_loss, count, out_loss, out_count);
  scatter_kernel<<<BATCH, 256, 0, stream>>>(x, target, row_logZ, row_correct,
                                            out_grad, out_count);
}